// Round 8
// baseline (709.105 us; speedup 1.0000x reference)
//
#include <hip/hip_runtime.h>
#include <hip/hip_cooperative_groups.h>
#include <cstdint>

// MoE: B=16384 rows, D=2048 feat, E=16 experts, C=64 classes/expert.
// R11: R10 = 262us best; all our kernels below the poison-fill top-5 cutoff;
// stack ~183us vs ~70us component floor -> the slack is structural (7 graph
// nodes + partial round-trips + redundant buffers). Fuse EVERYTHING into one
// cooperative kernel (doc-blessed hipLaunchCooperativeKernel), 512 blocks x
// 512 thr, launch_bounds(512,4) => VGPR<=128 => exactly 2 blocks/CU
// co-resident. Phases (grid.sync between):
//  A: pack ew -> fragment order (1 item/thread) + zero counters. cwP deleted
//     (coarse converts the 128KB L2-hot cw inline).
//  B: coarse 32 rows/block (2 groups x 4 K-quarter waves, R10 inner loop,
//     2-deep A prefetch) + bias/argmax + inlined routing atomics.
//  C: expert GEMM (R10 fragment code, 8 waves x 16 rows, acc=32 VGPR),
//     grid-stride worker loop over (item,kz); schedule derived per-block
//     from cnt via LDS prefix.
//  D: finish_rows verbatim, grid-strided.
// Fallback: if cooperative launch errors, run the proven R10 5-kernel path.
// f16x3 scheme (R6-R10 proven): a = hi + lo*2^-11, lo prescaled by 2048;
// accH = hi*hi, accC = hi*lo' + lo'*hi; y = accH + accC/2048.
// Fragment convention (validated): A/B frag = 8 contiguous k at row/col
// (lane&15), k-base (lane>>4)*8; D elem = (row=(lane>>4)*4+reg, col=lane&15).
namespace cg = cooperative_groups;

typedef _Float16 f16;
typedef f16 f16x8 __attribute__((ext_vector_type(8)));
typedef float f32x4 __attribute__((ext_vector_type(4)));
#define MFMA16(a, b, c) __builtin_amdgcn_mfma_f32_16x16x32_f16((a), (b), (c), 0, 0, 0)

static constexpr int B_ = 16384;
static constexpr int D_ = 2048;
static constexpr int E_ = 16;
static constexpr int C_ = 64;
static constexpr float LSC = 2048.0f;
static constexpr float ILSC = 1.0f / 2048.0f;
static constexpr int GRID = 512;
static constexpr int TPB = 512;
static constexpr int TR_E = 128;   // expert tile rows
static constexpr int SK_E = 8;     // expert split-K
static constexpr int NCHG = D_ / 32;
static constexpr int MAXITEMS = (B_ / TR_E) + E_;  // 144

__device__ __forceinline__ void cvt_hl(const float4 x, const float4 y,
                                       f16x8& h, f16x8& l) {
  const float av[8] = {x.x, x.y, x.z, x.w, y.x, y.y, y.z, y.w};
#pragma unroll
  for (int j = 0; j < 8; ++j) {
    const f16 hh = (f16)av[j];
    h[j] = hh;
    l[j] = (f16)((av[j] - (float)hh) * LSC);
  }
}

// ======================= cooperative mega-kernel ==========================
__global__ __launch_bounds__(512, 4) void moe_mega(
    const float* __restrict__ feat, const float* __restrict__ cw,
    const float* __restrict__ cb, const float* __restrict__ ew,
    const float* __restrict__ eb, f16* __restrict__ ewPH,
    f16* __restrict__ ewPL, float* __restrict__ out0,
    float* __restrict__ out1, float* __restrict__ out2,
    float* __restrict__ out3, int* __restrict__ cnt,
    int* __restrict__ rowList, int* __restrict__ eidArr,
    float* __restrict__ ypartRest) {
  cg::grid_group grid = cg::this_grid();
  const int tid = threadIdx.x;
  const int bid = blockIdx.x;

  __shared__ float red[8 * 256];  // 8 KB coarse reduce
  __shared__ int lcnt[E_], lbase[E_];
  __shared__ int rIdx[TR_E];
  __shared__ int cntS[E_], offsS[E_ + 1];

  // ---- Phase A: pack ew into fragment order; zero counters ----
  {
    const int t = bid * TPB + tid;  // 0..262143 == # f16x8 items of ew
    const int lane = t & 63;
    const int ct = (t >> 6) & 3;
    const int ch = (t >> 8) & 63;
    const int e = t >> 14;
    const int rl = lane & 15, kq = lane >> 4;
    const float* src =
        ew + ((size_t)e * C_ + ct * 16 + rl) * D_ + ch * 32 + kq * 8;
    const float4 v0 = *(const float4*)src;
    const float4 v1 = *(const float4*)(src + 4);
    f16x8 h8, l8;
    cvt_hl(v0, v1, h8, l8);
    *(f16x8*)(ewPH + (size_t)t * 8) = h8;
    *(f16x8*)(ewPL + (size_t)t * 8) = l8;
    if (t < 32) cnt[t] = 0;
  }
  __threadfence();
  grid.sync();

  // ---- Phase B: coarse GEMM (32 rows/block) + argmax + routing ----
  {
    const int w = tid >> 6;
    const int lane = tid & 63;
    const int rl = lane & 15, kq = lane >> 4;
    const int g = w >> 2;   // row group
    const int q = w & 3;    // K quarter (512 = 16 chunks)
    const int row = bid * 32 + g * 16 + rl;
    const int k0 = q * 512;

    const float* fr = feat + (size_t)row * D_ + k0 + kq * 8;
    const float* br = cw + (size_t)rl * D_ + k0 + kq * 8;  // L2-hot 128 KB

    f32x4 aH = {0.f, 0.f, 0.f, 0.f};
    f32x4 aC = {0.f, 0.f, 0.f, 0.f};
    float4 pA[2][2];
    pA[0][0] = *(const float4*)(fr);
    pA[0][1] = *(const float4*)(fr + 4);
    pA[1][0] = *(const float4*)(fr + 32);
    pA[1][1] = *(const float4*)(fr + 36);
    float4 pB0 = *(const float4*)(br);
    float4 pB1 = *(const float4*)(br + 4);
#pragma unroll
    for (int ch = 0; ch < 16; ++ch) {
      const int cur = ch & 1;  // compile-time after full unroll
      const float4 c0 = pA[cur][0], c1 = pA[cur][1];
      const float4 b0 = pB0, b1 = pB1;
      if (ch + 2 < 16) {
        pA[cur][0] = *(const float4*)(fr + (ch + 2) * 32);
        pA[cur][1] = *(const float4*)(fr + (ch + 2) * 32 + 4);
      }
      if (ch + 1 < 16) {
        pB0 = *(const float4*)(br + (ch + 1) * 32);
        pB1 = *(const float4*)(br + (ch + 1) * 32 + 4);
      }
      f16x8 h8, l8, bh, bl;
      cvt_hl(c0, c1, h8, l8);
      cvt_hl(b0, b1, bh, bl);
      aH = MFMA16(h8, bh, aH);
      aC = MFMA16(h8, bl, aC);
      aC = MFMA16(l8, bh, aC);
    }
#pragma unroll
    for (int reg = 0; reg < 4; ++reg)
      red[w * 256 + (kq * 4 + reg) * 16 + rl] = aH[reg] + aC[reg] * ILSC;
  }
  if (tid < E_) lcnt[tid] = 0;
  __syncthreads();
  {
    const int e = tid & 15;
    const int lrow = (tid >> 4) & 15;
    const int g = tid >> 8;
    float val = cb[e];
#pragma unroll
    for (int q = 0; q < 4; ++q) val += red[(g * 4 + q) * 256 + (tid & 255)];
    const int grow = bid * 32 + g * 16 + lrow;
    out0[(size_t)grow * E_ + e] = val;
    float av2 = val;
    int ai = e;
#pragma unroll
    for (int off = 8; off; off >>= 1) {
      const float ov = __shfl_xor(av2, off, 16);
      const int oi = __shfl_xor(ai, off, 16);
      if (ov > av2 || (ov == av2 && oi < ai)) { av2 = ov; ai = oi; }
    }
    int best = -1, lpos = 0;
    if (e == 0) {
      out1[grow] = (float)ai;
      eidArr[grow] = ai;
      best = ai;
      lpos = atomicAdd(&lcnt[ai], 1);
    }
    __syncthreads();
    if (tid < E_) lbase[tid] = atomicAdd(&cnt[tid], lcnt[tid]);
    __syncthreads();
    if (best >= 0) rowList[best * B_ + lbase[best] + lpos] = grow;
  }
  __threadfence();
  grid.sync();

  // ---- Phase C: expert GEMM over grid-stride (item, kz) workers ----
  {
    if (tid == 0) {  // 16-entry prefix of tile counts from cnt
      int acc = 0;
      for (int e2 = 0; e2 < E_; ++e2) {
        cntS[e2] = cnt[e2];
        offsS[e2] = acc;
        acc += (cntS[e2] + TR_E - 1) / TR_E;
      }
      offsS[E_] = acc;
    }
    __syncthreads();
    const int nW = offsS[E_] * SK_E;  // <= 1152
    const int w = tid >> 6;
    const int lane = tid & 63;
    const int rl = lane & 15, kq = lane >> 4;

    for (int wk = bid; wk < nW; wk += GRID) {
      const int kz = wk & 7;
      const int idx = wk >> 3;
      int e = 0;
#pragma unroll
      for (int j = 1; j < E_; ++j)
        if (idx >= offsS[j]) e = j;
      const int tile = idx - offsS[e];
      const int count = cntS[e];
      __syncthreads();  // protect rIdx reuse across workers
      if (tid < TR_E) {
        const int slot = tile * TR_E + tid;
        rIdx[tid] = (slot < count) ? rowList[e * B_ + slot] : 0;
      }
      __syncthreads();

      const int grow = rIdx[w * 16 + rl];
      const int k0 = kz * 256;
      const float* pa = feat + (size_t)grow * D_ + k0 + kq * 8;
      const f16* pbh = ewPH + ((size_t)e * NCHG + kz * 8) * 2048 + lane * 8;
      const f16* pbl = ewPL + ((size_t)e * NCHG + kz * 8) * 2048 + lane * 8;

      f32x4 accH[4], accC[4];
#pragma unroll
      for (int ct = 0; ct < 4; ++ct) {
        accH[ct] = (f32x4){0.f, 0.f, 0.f, 0.f};
        accC[ct] = (f32x4){0.f, 0.f, 0.f, 0.f};
      }
      float4 n0 = *(const float4*)(pa);
      float4 n1 = *(const float4*)(pa + 4);
#pragma unroll
      for (int ch = 0; ch < 8; ++ch) {
        const float4 c0 = n0, c1 = n1;
        if (ch + 1 < 8) {
          n0 = *(const float4*)(pa + (ch + 1) * 32);
          n1 = *(const float4*)(pa + (ch + 1) * 32 + 4);
        }
        f16x8 ah, al;
        cvt_hl(c0, c1, ah, al);
#pragma unroll
        for (int ct = 0; ct < 4; ++ct) {
          const f16x8 bh = *(const f16x8*)(pbh + ch * 2048 + ct * 512);
          const f16x8 bl = *(const f16x8*)(pbl + ch * 2048 + ct * 512);
          accH[ct] = MFMA16(ah, bh, accH[ct]);
          accC[ct] = MFMA16(ah, bl, accC[ct]);
          accC[ct] = MFMA16(al, bh, accC[ct]);
        }
      }
      float* pk = kz ? (ypartRest + (size_t)(kz - 1) * B_ * C_) : out2;
#pragma unroll
      for (int reg = 0; reg < 4; ++reg) {
        const int rloc = w * 16 + kq * 4 + reg;
        const int slot = tile * TR_E + rloc;
        if (slot < count) {
          const int g = rIdx[rloc];
#pragma unroll
          for (int ct = 0; ct < 4; ++ct)
            pk[(size_t)g * C_ + ct * 16 + rl] =
                accH[ct][reg] + accC[ct][reg] * ILSC;
        }
      }
    }
  }
  __threadfence();
  grid.sync();

  // ---- Phase D: reduce partials + bias + softmax + argmax ----
  {
    const int lane = tid & 63;
    const int wv = tid >> 6;
    for (int row = bid * 8 + wv; row < B_; row += GRID * 8) {
      const int eid = eidArr[row];
      float v = eb[eid * C_ + lane] + out2[(size_t)row * C_ + lane];
#pragma unroll
      for (int kz = 1; kz < SK_E; ++kz)
        v += ypartRest[((size_t)(kz - 1) * B_ + row) * C_ + lane];
      float m = v;
#pragma unroll
      for (int off = 32; off; off >>= 1) m = fmaxf(m, __shfl_xor(m, off, 64));
      const float p = __expf(v - m);
      float s = p;
#pragma unroll
      for (int off = 32; off; off >>= 1) s += __shfl_xor(s, off, 64);
      out2[(size_t)row * C_ + lane] = p / s;
      float av = v;
      int ai = lane;
#pragma unroll
      for (int off = 32; off; off >>= 1) {
        const float ov = __shfl_xor(av, off, 64);
        const int oi = __shfl_xor(ai, off, 64);
        if (ov > av || (ov == av && oi < ai)) { av = ov; ai = oi; }
      }
      if (lane == 0) out3[row] = (float)(ai + (eid << 6));
    }
  }
}

// ===================== R10 fallback path (proven, 262us) ==================
__global__ __launch_bounds__(256) void convert_pack(
    const float* __restrict__ cw, const float* __restrict__ ew,
    f16* __restrict__ cwPH, f16* __restrict__ cwPL,
    f16* __restrict__ ewPH, f16* __restrict__ ewPL) {
  const int g = blockIdx.x;
  const int tid = threadIdx.x;
  if (g < 16) {
    const int t = g * 256 + tid;
    const int ch = t >> 6;
    const int lane = t & 63;
    const int rl = lane & 15, kq = lane >> 4;
    const float* src = cw + (size_t)rl * D_ + ch * 32 + kq * 8;
    const float4 v0 = *(const float4*)src;
    const float4 v1 = *(const float4*)(src + 4);
    f16x8 h8, l8;
    cvt_hl(v0, v1, h8, l8);
    *(f16x8*)(cwPH + (size_t)t * 8) = h8;
    *(f16x8*)(cwPL + (size_t)t * 8) = l8;
  } else {
    const int t = (g - 16) * 256 + tid;
    const int lane = t & 63;
    const int ct = (t >> 6) & 3;
    const int ch = (t >> 8) & 63;
    const int e = t >> 14;
    const int rl = lane & 15, kq = lane >> 4;
    const float* src =
        ew + ((size_t)e * C_ + ct * 16 + rl) * D_ + ch * 32 + kq * 8;
    const float4 v0 = *(const float4*)src;
    const float4 v1 = *(const float4*)(src + 4);
    f16x8 h8, l8;
    cvt_hl(v0, v1, h8, l8);
    *(f16x8*)(ewPH + (size_t)t * 8) = h8;
    *(f16x8*)(ewPL + (size_t)t * 8) = l8;
  }
}

__global__ __launch_bounds__(512, 4) void coarse_fused_fb(
    const float* __restrict__ feat, const f16* __restrict__ cwPH,
    const f16* __restrict__ cwPL, const float* __restrict__ cb,
    float* __restrict__ out0, float* __restrict__ out1,
    int* __restrict__ eidArr) {
  __shared__ float red[8 * 256];
  const int tid = threadIdx.x;
  const int w = tid >> 6;
  const int lane = tid & 63;
  const int rl = lane & 15;
  const int kq = lane >> 4;
  const int row = blockIdx.x * 16 + rl;
  const float* fr = feat + (size_t)row * D_ + w * 256 + kq * 8;
  const f16* pbh = cwPH + (size_t)(w * 8) * 512 + lane * 8;
  const f16* pbl = cwPL + (size_t)(w * 8) * 512 + lane * 8;
  f32x4 aH = {0.f, 0.f, 0.f, 0.f};
  f32x4 aC = {0.f, 0.f, 0.f, 0.f};
  float4 pA[2][2];
  pA[0][0] = *(const float4*)(fr);
  pA[0][1] = *(const float4*)(fr + 4);
  pA[1][0] = *(const float4*)(fr + 32);
  pA[1][1] = *(const float4*)(fr + 36);
  f16x8 bh = *(const f16x8*)(pbh);
  f16x8 bl = *(const f16x8*)(pbl);
#pragma unroll
  for (int ch = 0; ch < 8; ++ch) {
    const int cur = ch & 1;
    const float4 c0 = pA[cur][0], c1 = pA[cur][1];
    const f16x8 bhc = bh, blc = bl;
    if (ch + 2 < 8) {
      pA[cur][0] = *(const float4*)(fr + (ch + 2) * 32);
      pA[cur][1] = *(const float4*)(fr + (ch + 2) * 32 + 4);
    }
    if (ch + 1 < 8) {
      bh = *(const f16x8*)(pbh + (ch + 1) * 512);
      bl = *(const f16x8*)(pbl + (ch + 1) * 512);
    }
    f16x8 h8, l8;
    cvt_hl(c0, c1, h8, l8);
    aH = MFMA16(h8, bhc, aH);
    aC = MFMA16(h8, blc, aC);
    aC = MFMA16(l8, bhc, aC);
  }
#pragma unroll
  for (int reg = 0; reg < 4; ++reg)
    red[w * 256 + (kq * 4 + reg) * 16 + rl] = aH[reg] + aC[reg] * ILSC;
  __syncthreads();
  if (tid < 256) {
    const int e = tid & 15;
    const int lrow = tid >> 4;
    float val = cb[e];
#pragma unroll
    for (int ww = 0; ww < 8; ++ww) val += red[ww * 256 + tid];
    const int grow = blockIdx.x * 16 + lrow;
    out0[(size_t)grow * E_ + e] = val;
    float av2 = val;
    int ai = e;
#pragma unroll
    for (int off = 8; off; off >>= 1) {
      const float ov = __shfl_xor(av2, off, 16);
      const int oi = __shfl_xor(ai, off, 16);
      if (ov > av2 || (ov == av2 && oi < ai)) { av2 = ov; ai = oi; }
    }
    if (e == 0) {
      out1[grow] = (float)ai;
      eidArr[grow] = ai;
    }
  }
}

__global__ __launch_bounds__(256) void route_build(
    const int* __restrict__ eidArr, int* __restrict__ cnt,
    int* __restrict__ rowList) {
  __shared__ int lcnt[E_];
  __shared__ int lbase[E_];
  const int tid = threadIdx.x;
  if (tid < E_) lcnt[tid] = 0;
  __syncthreads();
  const int row = blockIdx.x * 256 + tid;
  const int best = eidArr[row];
  const int lpos = atomicAdd(&lcnt[best], 1);
  __syncthreads();
  if (tid < E_) lbase[tid] = atomicAdd(&cnt[tid], lcnt[tid]);
  __syncthreads();
  rowList[best * B_ + lbase[best] + lpos] = row;
}

__global__ void make_schedule(const int* __restrict__ cnt,
                              int* __restrict__ sched,
                              int* __restrict__ nItems) {
  __shared__ int tiles[E_];
  __shared__ int offs[E_];
  const int t = threadIdx.x;
  if (t < E_) tiles[t] = (cnt[t] + TR_E - 1) / TR_E;
  __syncthreads();
  if (t == 0) {
    int acc = 0;
    for (int e = 0; e < E_; ++e) { offs[e] = acc; acc += tiles[e]; }
    *nItems = acc;
  }
  __syncthreads();
  if (t < E_) {
    const int o = offs[t], n = tiles[t];
    for (int k = 0; k < n; ++k) sched[o + k] = t | (k << 8);
  }
}

__global__ __launch_bounds__(256) void expert_gemm_fb(
    const float* __restrict__ feat, const f16* __restrict__ ewPH,
    const f16* __restrict__ ewPL, const int* __restrict__ rowList,
    const int* __restrict__ cnt, const int* __restrict__ sched,
    const int* __restrict__ nItems, float* __restrict__ part0,
    float* __restrict__ partRest) {
  __shared__ int rIdx[TR_E];
  const int b = blockIdx.x;
  const int kz = b % SK_E;
  const int item = b / SK_E;
  if (item >= *nItems) return;
  const int s = sched[item];
  const int e = s & 255;
  const int tile = s >> 8;
  const int count = cnt[e];
  const int tid = threadIdx.x;
  if (tid < TR_E) {
    const int slot = tile * TR_E + tid;
    rIdx[tid] = (slot < count) ? rowList[e * B_ + slot] : 0;
  }
  __syncthreads();
  const int lane = tid & 63;
  const int w = tid >> 6;
  const int rl = lane & 15;
  const int kq = lane >> 4;
  const int grow0 = rIdx[w * 32 + rl];
  const int grow1 = rIdx[w * 32 + 16 + rl];
  const int k0 = kz * 256;
  const float* pa0 = feat + (size_t)grow0 * D_ + k0 + kq * 8;
  const float* pa1 = feat + (size_t)grow1 * D_ + k0 + kq * 8;
  const f16* pbh = ewPH + ((size_t)e * NCHG + kz * 8) * 2048 + lane * 8;
  const f16* pbl = ewPL + ((size_t)e * NCHG + kz * 8) * 2048 + lane * 8;
  f32x4 accH[2][4], accC[2][4];
#pragma unroll
  for (int s2 = 0; s2 < 2; ++s2)
#pragma unroll
    for (int ct = 0; ct < 4; ++ct) {
      accH[s2][ct] = (f32x4){0.f, 0.f, 0.f, 0.f};
      accC[s2][ct] = (f32x4){0.f, 0.f, 0.f, 0.f};
    }
  float4 n0a = *(const float4*)(pa0);
  float4 n0b = *(const float4*)(pa0 + 4);
  float4 n1a = *(const float4*)(pa1);
  float4 n1b = *(const float4*)(pa1 + 4);
#pragma unroll
  for (int ch = 0; ch < 8; ++ch) {
    const float4 c0a = n0a, c0b = n0b, c1a = n1a, c1b = n1b;
    if (ch + 1 < 8) {
      const int kn = (ch + 1) * 32;
      n0a = *(const float4*)(pa0 + kn);
      n0b = *(const float4*)(pa0 + kn + 4);
      n1a = *(const float4*)(pa1 + kn);
      n1b = *(const float4*)(pa1 + kn + 4);
    }
    f16x8 a0h, a0l, a1h, a1l;
    cvt_hl(c0a, c0b, a0h, a0l);
    cvt_hl(c1a, c1b, a1h, a1l);
#pragma unroll
    for (int ct = 0; ct < 4; ++ct) {
      const f16x8 bh = *(const f16x8*)(pbh + ch * 2048 + ct * 512);
      const f16x8 bl = *(const f16x8*)(pbl + ch * 2048 + ct * 512);
      accH[0][ct] = MFMA16(a0h, bh, accH[0][ct]);
      accC[0][ct] = MFMA16(a0h, bl, accC[0][ct]);
      accC[0][ct] = MFMA16(a0l, bh, accC[0][ct]);
      accH[1][ct] = MFMA16(a1h, bh, accH[1][ct]);
      accC[1][ct] = MFMA16(a1h, bl, accC[1][ct]);
      accC[1][ct] = MFMA16(a1l, bh, accC[1][ct]);
    }
  }
  float* pk = kz ? (partRest + (size_t)(kz - 1) * B_ * C_) : part0;
#pragma unroll
  for (int s2 = 0; s2 < 2; ++s2)
#pragma unroll
    for (int reg = 0; reg < 4; ++reg) {
      const int rloc = w * 32 + s2 * 16 + kq * 4 + reg;
      const int slot = tile * TR_E + rloc;
      if (slot < count) {
        const int g = rIdx[rloc];
#pragma unroll
        for (int ct = 0; ct < 4; ++ct)
          pk[(size_t)g * C_ + ct * 16 + rl] =
              accH[s2][ct][reg] + accC[s2][ct][reg] * ILSC;
      }
    }
}

__global__ __launch_bounds__(256) void finish_rows_fb(
    const float* __restrict__ ypart0, const float* __restrict__ ypartRest,
    const float* __restrict__ eb, const int* __restrict__ eidArr,
    float* __restrict__ out2, float* __restrict__ out3) {
  const int lane = threadIdx.x & 63;
  const int row = (blockIdx.x * 256 + threadIdx.x) >> 6;
  const int eid = eidArr[row];
  float v = eb[eid * C_ + lane];
  v += ypart0[(size_t)row * C_ + lane];
#pragma unroll
  for (int kz = 1; kz < SK_E; ++kz)
    v += ypartRest[((size_t)(kz - 1) * B_ + row) * C_ + lane];
  float m = v;
#pragma unroll
  for (int off = 32; off; off >>= 1) m = fmaxf(m, __shfl_xor(m, off, 64));
  const float p = __expf(v - m);
  float s = p;
#pragma unroll
  for (int off = 32; off; off >>= 1) s += __shfl_xor(s, off, 64);
  out2[(size_t)row * C_ + lane] = p / s;
  float av = v;
  int ai = lane;
#pragma unroll
  for (int off = 32; off; off >>= 1) {
    const float ov = __shfl_xor(av, off, 64);
    const int oi = __shfl_xor(ai, off, 64);
    if (ov > av || (ov == av && oi < ai)) { av = ov; ai = oi; }
  }
  if (lane == 0) out3[row] = (float)(ai + (eid << 6));
}

extern "C" void kernel_launch(void* const* d_in, const int* in_sizes, int n_in,
                              void* d_out, int out_size, void* d_ws,
                              size_t ws_size, hipStream_t stream) {
  const float* feat = (const float*)d_in[0];
  const float* cw = (const float*)d_in[1];
  const float* cb = (const float*)d_in[2];
  const float* ew = (const float*)d_in[3];
  const float* eb = (const float*)d_in[4];

  float* out0 = (float*)d_out;
  float* out1 = out0 + (size_t)B_ * E_;
  float* out2 = out1 + B_;
  float* out3 = out2 + (size_t)B_ * C_;

  // ws layout (union of mega + fallback): ~40 MB
  char* p = (char*)d_ws;
  f16* ewPH = (f16*)p;    p += (size_t)E_ * C_ * D_ * 2;   // 4 MB
  f16* ewPL = (f16*)p;    p += (size_t)E_ * C_ * D_ * 2;   // 4 MB
  f16* cwPH = (f16*)p;    p += (size_t)E_ * D_ * 2;        // 64 KB (fallback)
  f16* cwPL = (f16*)p;    p += (size_t)E_ * D_ * 2;        // 64 KB (fallback)
  float* ypartRest = (float*)p; p += (size_t)(SK_E - 1) * B_ * C_ * 4;  // 29.4 MB
  int* rowList = (int*)p; p += (size_t)E_ * B_ * 4;        // 1 MB
  int* cnt = (int*)p;     p += 64 * 4;
  int* eidArr = (int*)p;  p += (size_t)B_ * 4;
  int* sched = (int*)p;   p += 512 * 4;
  int* nItems = (int*)p;

  void* kargs[] = {(void*)&feat, (void*)&cw,   (void*)&cb,
                   (void*)&ew,   (void*)&eb,   (void*)&ewPH,
                   (void*)&ewPL, (void*)&out0, (void*)&out1,
                   (void*)&out2, (void*)&out3, (void*)&cnt,
                   (void*)&rowList, (void*)&eidArr, (void*)&ypartRest};
  hipError_t err = hipLaunchCooperativeKernel(
      (void*)moe_mega, dim3(GRID), dim3(TPB), kargs, 0, stream);
  if (err != hipSuccess) {
    (void)hipGetLastError();  // clear sticky error; run proven R10 path
    hipMemsetAsync(cnt, 0, E_ * sizeof(int), stream);
    convert_pack<<<16 + 1024, 256, 0, stream>>>(cw, ew, cwPH, cwPL, ewPH,
                                                ewPL);
    coarse_fused_fb<<<B_ / 16, 512, 0, stream>>>(feat, cwPH, cwPL, cb, out0,
                                                 out1, eidArr);
    route_build<<<B_ / 256, 256, 0, stream>>>(eidArr, cnt, rowList);
    make_schedule<<<1, 64, 0, stream>>>(cnt, sched, nItems);
    expert_gemm_fb<<<MAXITEMS * SK_E, 256, 0, stream>>>(
        feat, ewPH, ewPL, rowList, cnt, sched, nItems, out2, ypartRest);
    finish_rows_fb<<<(B_ * 64) / 256, 256, 0, stream>>>(out2, ypartRest, eb,
                                                        eidArr, out2, out3);
  }
}

// Round 9
// 323.153 us; speedup vs baseline: 2.1943x; 2.1943x over previous
//
#include <hip/hip_runtime.h>
#include <cstdint>

// MoE: B=16384 rows, D=2048 feat, E=16 experts, C=64 classes/expert.
// R12: R11 mega-kernel failed (558us: VGPR=56 -> prefetch never materialized;
// raw-cw 16-row scatter reintroduced). Revert to R10's proven 262us skeleton
// and harvest the structural slack WITHOUT touching the proven inner loops:
//  - expert: TR=64 items over FULL K (no split-K): 8 waves = 4 row-groups x
//    2 K-halves, 16KB LDS merge, then R9-validated fused bias+softmax+argmax
//    epilogue -> out2/out3 directly. Deletes ypartRest (29MB w + 33MB r),
//    finish_rows, and a launch tail. Inner loop = R10 fragment code verbatim.
//  - coarse: R10 verbatim + R9-validated fused routing (block-aggregated
//    atomics) + last-done-block schedule build. Deletes route_build,
//    make_schedule, eidArr.
//  - convert_pack zeroes counters (deletes memset launch).
// 3 launches total. All math bitwise-identical to passing kernels.
// f16x3 scheme (R6-R10 proven): a = hi + lo*2^-11, lo prescaled by 2048;
// accH = hi*hi, accC = hi*lo' + lo'*hi; y = accH + accC/2048.
// Fragment convention (validated): A/B frag = 8 contiguous k at row/col
// (lane&15), k-base (lane>>4)*8; D elem = (row=(lane>>4)*4+reg, col=lane&15).
typedef _Float16 f16;
typedef f16 f16x8 __attribute__((ext_vector_type(8)));
typedef float f32x4 __attribute__((ext_vector_type(4)));
#define MFMA16(a, b, c) __builtin_amdgcn_mfma_f32_16x16x32_f16((a), (b), (c), 0, 0, 0)

static constexpr int B_ = 16384;
static constexpr int D_ = 2048;
static constexpr int E_ = 16;
static constexpr int C_ = 64;
static constexpr float LSC = 2048.0f;
static constexpr float ILSC = 1.0f / 2048.0f;
static constexpr int NCHG = D_ / 32;     // 64 global k-chunks
static constexpr int TR_X = 64;          // expert tile rows (full-K items)
static constexpr int MAXI_X = B_ / TR_X + E_;  // 272 worst case

__device__ __forceinline__ void cvt_hl(const float4 x, const float4 y,
                                       f16x8& h, f16x8& l) {
  const float av[8] = {x.x, x.y, x.z, x.w, y.x, y.y, y.z, y.w};
#pragma unroll
  for (int j = 0; j < 8; ++j) {
    const f16 hh = (f16)av[j];
    h[j] = hh;
    l[j] = (f16)((av[j] - (float)hh) * LSC);
  }
}

// ---- weight conversion INTO FRAGMENT-PACKED layout + counter zeroing ----
// cwP[ch(64)][lane(64)][8]; ewP[e][ch(64)][ct(4)][lane(64)][8].  B loads in
// both GEMMs become base + lane*8 -> one fully-coalesced 1KB instruction.
__global__ __launch_bounds__(256) void convert_pack(
    const float* __restrict__ cw, const float* __restrict__ ew,
    f16* __restrict__ cwPH, f16* __restrict__ cwPL,
    f16* __restrict__ ewPH, f16* __restrict__ ewPL, int* __restrict__ cnt) {
  const int g = blockIdx.x;
  const int tid = threadIdx.x;
  if (g == 0 && tid < 32) cnt[tid] = 0;  // cnt[0..15] + doneCnt + spare
  if (g < 16) {  // cw: 64 chunks * 64 lanes
    const int t = g * 256 + tid;
    const int ch = t >> 6;
    const int lane = t & 63;
    const int rl = lane & 15, kq = lane >> 4;
    const float* src = cw + (size_t)rl * D_ + ch * 32 + kq * 8;
    const float4 v0 = *(const float4*)src;
    const float4 v1 = *(const float4*)(src + 4);
    f16x8 h8, l8;
    cvt_hl(v0, v1, h8, l8);
    *(f16x8*)(cwPH + (size_t)t * 8) = h8;
    *(f16x8*)(cwPL + (size_t)t * 8) = l8;
  } else {       // ew: 16e * 64ch * 4ct * 64lane
    const int t = (g - 16) * 256 + tid;
    const int lane = t & 63;
    const int ct = (t >> 6) & 3;
    const int ch = (t >> 8) & 63;
    const int e = t >> 14;
    const int rl = lane & 15, kq = lane >> 4;
    const float* src =
        ew + ((size_t)e * C_ + ct * 16 + rl) * D_ + ch * 32 + kq * 8;
    const float4 v0 = *(const float4*)src;
    const float4 v1 = *(const float4*)(src + 4);
    f16x8 h8, l8;
    cvt_hl(v0, v1, h8, l8);
    *(f16x8*)(ewPH + (size_t)t * 8) = h8;
    *(f16x8*)(ewPL + (size_t)t * 8) = l8;
  }
}

// ---- coarse GEMM (R10 verbatim) + fused routing + schedule build ----
// 1024 blocks x 512 thr. Block owns 16 rows; wave w owns K chunks
// [w*8, w*8+8). A 2-deep static prefetch; B packed (coalesced, L2-hot).
// launch_bounds(512,4): VGPR cap 128 so the prefetch materializes.
__global__ __launch_bounds__(512, 4) void coarse_fused(
    const float* __restrict__ feat, const f16* __restrict__ cwPH,
    const f16* __restrict__ cwPL, const float* __restrict__ cb,
    float* __restrict__ out0, float* __restrict__ out1,
    int* __restrict__ cnt, int* __restrict__ rowList,
    int* __restrict__ sched, int* __restrict__ nItems,
    int* __restrict__ doneCnt) {
  __shared__ float red[8 * 256];
  __shared__ int lcnt[E_], lbase[E_], tiles[E_], offs[E_];
  __shared__ int isLast;
  const int tid = threadIdx.x;
  const int w = tid >> 6;
  const int lane = tid & 63;
  const int rl = lane & 15;
  const int kq = lane >> 4;
  const int row = blockIdx.x * 16 + rl;
  const float* fr = feat + (size_t)row * D_ + w * 256 + kq * 8;
  const f16* pbh = cwPH + (size_t)(w * 8) * 512 + lane * 8;
  const f16* pbl = cwPL + (size_t)(w * 8) * 512 + lane * 8;

  f32x4 aH = {0.f, 0.f, 0.f, 0.f};
  f32x4 aC = {0.f, 0.f, 0.f, 0.f};
  float4 pA[2][2];
  pA[0][0] = *(const float4*)(fr);
  pA[0][1] = *(const float4*)(fr + 4);
  pA[1][0] = *(const float4*)(fr + 32);
  pA[1][1] = *(const float4*)(fr + 36);
  f16x8 bh = *(const f16x8*)(pbh);
  f16x8 bl = *(const f16x8*)(pbl);
#pragma unroll
  for (int ch = 0; ch < 8; ++ch) {
    const int cur = ch & 1;  // compile-time after full unroll
    const float4 c0 = pA[cur][0], c1 = pA[cur][1];
    const f16x8 bhc = bh, blc = bl;
    if (ch + 2 < 8) {
      pA[cur][0] = *(const float4*)(fr + (ch + 2) * 32);
      pA[cur][1] = *(const float4*)(fr + (ch + 2) * 32 + 4);
    }
    if (ch + 1 < 8) {
      bh = *(const f16x8*)(pbh + (ch + 1) * 512);
      bl = *(const f16x8*)(pbl + (ch + 1) * 512);
    }
    f16x8 h8, l8;
    cvt_hl(c0, c1, h8, l8);
    aH = MFMA16(h8, bhc, aH);
    aC = MFMA16(h8, blc, aC);
    aC = MFMA16(l8, bhc, aC);
  }
#pragma unroll
  for (int reg = 0; reg < 4; ++reg)
    red[w * 256 + (kq * 4 + reg) * 16 + rl] = aH[reg] + aC[reg] * ILSC;
  if (tid < E_) lcnt[tid] = 0;
  __syncthreads();

  int best = -1, lpos = 0, grow = 0;
  if (tid < 256) {
    const int e = tid & 15;
    const int lrow = tid >> 4;
    float val = cb[e];
#pragma unroll
    for (int ww = 0; ww < 8; ++ww) val += red[ww * 256 + tid];
    grow = blockIdx.x * 16 + lrow;
    out0[(size_t)grow * E_ + e] = val;
    // argmax over 16 experts (16-lane group), first-occurrence tie-break
    float av2 = val;
    int ai = e;
#pragma unroll
    for (int off = 8; off; off >>= 1) {
      const float ov = __shfl_xor(av2, off, 16);
      const int oi = __shfl_xor(ai, off, 16);
      if (ov > av2 || (ov == av2 && oi < ai)) { av2 = ov; ai = oi; }
    }
    if (e == 0) {
      out1[grow] = (float)ai;
      best = ai;
      lpos = atomicAdd(&lcnt[ai], 1);
    }
  }
  __syncthreads();
  if (tid < E_) lbase[tid] = atomicAdd(&cnt[tid], lcnt[tid]);
  __syncthreads();
  if (best >= 0) rowList[best * B_ + lbase[best] + lpos] = grow;

  // ---- last-done block builds the (e, tile64) schedule ----
  __syncthreads();
  if (tid == 0) {
    __threadfence();  // publish this block's cnt atomics + rowList stores
    const int d = atomicAdd(doneCnt, 1);
    isLast = (d == (int)gridDim.x - 1) ? 1 : 0;
  }
  __syncthreads();
  if (isLast) {
    if (tid < E_)
      tiles[tid] = (atomicAdd(&cnt[tid], 0) + TR_X - 1) / TR_X;
    __syncthreads();
    if (tid == 0) {
      int acc = 0;
      for (int e2 = 0; e2 < E_; ++e2) { offs[e2] = acc; acc += tiles[e2]; }
      *nItems = acc;
    }
    __syncthreads();
    if (tid < E_) {
      const int o = offs[tid], n = tiles[tid];
      for (int k = 0; k < n; ++k) sched[o + k] = tid | (k << 8);
    }
  }
}

// ---- expert GEMM + finish, fully fused, NO split-K ----
// Item = 64 routed rows of one expert (<=272 items). 512 thr = 8 waves:
// wave (rg = w>>1, kh = w&1) computes rows [rg*16, rg*16+16) x K-half kh.
// Inner loop = R10 expert fragment code verbatim (A 1-deep prefetch from
// L3-warm f32 feat, packed-B inline). K-halves merged via 16KB LDS (fixed
// order); epilogue (kh==0) = R9-validated bias+softmax+argmax -> out2/out3.
__global__ __launch_bounds__(512) void expert_fused(
    const float* __restrict__ feat, const f16* __restrict__ ewPH,
    const f16* __restrict__ ewPL, const float* __restrict__ eb,
    const int* __restrict__ rowList, const int* __restrict__ cnt,
    const int* __restrict__ sched, const int* __restrict__ nItems,
    float* __restrict__ out2, float* __restrict__ out3) {
  __shared__ int rIdx[TR_X];
  __shared__ float yred[TR_X * C_];  // 16 KB
  const int item = blockIdx.x;
  if (item >= *nItems) return;  // uniform per block, before any barrier
  const int s = sched[item];
  const int e = s & 255;
  const int tile = s >> 8;
  const int count = cnt[e];

  const int tid = threadIdx.x;
  if (tid < TR_X) {
    const int slot = tile * TR_X + tid;
    rIdx[tid] = (slot < count) ? rowList[e * B_ + slot] : 0;
  }
  __syncthreads();

  const int lane = tid & 63;
  const int w = tid >> 6;
  const int rg = w >> 1;   // row group (4)
  const int kh = w & 1;    // K half
  const int rl = lane & 15;
  const int kq = lane >> 4;

  const int growA = rIdx[rg * 16 + rl];
  const int k0 = kh * (D_ / 2);          // 32 chunks per half
  const float* pa = feat + (size_t)growA * D_ + k0 + kq * 8;
  const f16* pbh = ewPH + ((size_t)e * NCHG + kh * 32) * 2048 + lane * 8;
  const f16* pbl = ewPL + ((size_t)e * NCHG + kh * 32) * 2048 + lane * 8;

  f32x4 accH[4], accC[4];
#pragma unroll
  for (int ct = 0; ct < 4; ++ct) {
    accH[ct] = (f32x4){0.f, 0.f, 0.f, 0.f};
    accC[ct] = (f32x4){0.f, 0.f, 0.f, 0.f};
  }

  float4 n0 = *(const float4*)(pa);
  float4 n1 = *(const float4*)(pa + 4);
#pragma unroll
  for (int ch = 0; ch < 32; ++ch) {
    const float4 c0 = n0, c1 = n1;
    if (ch + 1 < 32) {
      n0 = *(const float4*)(pa + (ch + 1) * 32);
      n1 = *(const float4*)(pa + (ch + 1) * 32 + 4);
    }
    f16x8 ah, al;
    cvt_hl(c0, c1, ah, al);
#pragma unroll
    for (int ct = 0; ct < 4; ++ct) {
      const f16x8 bh = *(const f16x8*)(pbh + ch * 2048 + ct * 512);
      const f16x8 bl = *(const f16x8*)(pbl + ch * 2048 + ct * 512);
      accH[ct] = MFMA16(ah, bh, accH[ct]);
      accC[ct] = MFMA16(ah, bl, accC[ct]);
      accC[ct] = MFMA16(al, bh, accC[ct]);
    }
  }

  // merge K-halves: kh=1 waves deposit, kh=0 waves reduce (fixed order)
  if (kh == 1) {
#pragma unroll
    for (int ct = 0; ct < 4; ++ct)
#pragma unroll
      for (int reg = 0; reg < 4; ++reg)
        yred[(rg * 16 + kq * 4 + reg) * C_ + ct * 16 + rl] =
            accH[ct][reg] + accC[ct][reg] * ILSC;
  }
  __syncthreads();
  if (kh == 0) {
#pragma unroll
    for (int reg = 0; reg < 4; ++reg) {
      const int lrow = rg * 16 + kq * 4 + reg;  // tile-local row
      float v[4];
#pragma unroll
      for (int ct = 0; ct < 4; ++ct)
        v[ct] = accH[ct][reg] + accC[ct][reg] * ILSC +
                yred[lrow * C_ + ct * 16 + rl] + eb[e * C_ + ct * 16 + rl];
      // softmax over the row's 64 cols (4 regs x 16 lanes sharing kq)
      float m = fmaxf(fmaxf(v[0], v[1]), fmaxf(v[2], v[3]));
#pragma unroll
      for (int off = 8; off; off >>= 1) m = fmaxf(m, __shfl_xor(m, off, 16));
      float p[4], ssum = 0.f;
#pragma unroll
      for (int ct = 0; ct < 4; ++ct) { p[ct] = __expf(v[ct] - m); ssum += p[ct]; }
#pragma unroll
      for (int off = 8; off; off >>= 1) ssum += __shfl_xor(ssum, off, 16);
      const int slot = tile * TR_X + lrow;
      const int g = rIdx[lrow];
      if (slot < count) {
#pragma unroll
        for (int ct = 0; ct < 4; ++ct)
          out2[(size_t)g * C_ + ct * 16 + rl] = p[ct] / ssum;
      }
      // first-occurrence argmax over the row (col = ct*16 + rl)
      float av = v[0];
      int ai = rl;
#pragma unroll
      for (int ct = 1; ct < 4; ++ct)
        if (v[ct] > av) { av = v[ct]; ai = ct * 16 + rl; }
#pragma unroll
      for (int off = 8; off; off >>= 1) {
        const float ov = __shfl_xor(av, off, 16);
        const int oi = __shfl_xor(ai, off, 16);
        if (ov > av || (ov == av && oi < ai)) { av = ov; ai = oi; }
      }
      if (slot < count && rl == 0) out3[g] = (float)(ai + (e << 6));
    }
  }
}

extern "C" void kernel_launch(void* const* d_in, const int* in_sizes, int n_in,
                              void* d_out, int out_size, void* d_ws,
                              size_t ws_size, hipStream_t stream) {
  const float* feat = (const float*)d_in[0];  // [B, D]
  const float* cw = (const float*)d_in[1];    // [E, D]
  const float* cb = (const float*)d_in[2];    // [E]
  const float* ew = (const float*)d_in[3];    // [E, C, D]
  const float* eb = (const float*)d_in[4];    // [E, C]

  float* out0 = (float*)d_out;           // coarse_output [B, E]
  float* out1 = out0 + (size_t)B_ * E_;  // expert_id [B] (as float)
  float* out2 = out1 + B_;               // local_preds [B, C]
  float* out3 = out2 + (size_t)B_ * C_;  // global_preds [B]

  // ws (~9.8 MB): packed f16 weights + routing metadata. No partials.
  char* p = (char*)d_ws;
  f16* ewPH = (f16*)p;    p += (size_t)E_ * C_ * D_ * 2;  // 4 MB
  f16* ewPL = (f16*)p;    p += (size_t)E_ * C_ * D_ * 2;  // 4 MB
  f16* cwPH = (f16*)p;    p += (size_t)E_ * D_ * 2;       // 64 KB
  f16* cwPL = (f16*)p;    p += (size_t)E_ * D_ * 2;       // 64 KB
  int* rowList = (int*)p; p += (size_t)E_ * B_ * 4;       // 1 MB
  int* cnt = (int*)p;     p += 64 * 4;  // cnt[0..15], doneCnt = cnt[16]
  int* sched = (int*)p;   p += 512 * 4;
  int* nItems = (int*)p;
  int* doneCnt = cnt + 16;

  // 1) weights -> fragment-packed f16 hi/lo + zero counters
  convert_pack<<<16 + 1024, 256, 0, stream>>>(cw, ew, cwPH, cwPL, ewPH, ewPL,
                                              cnt);
  // 2) coarse MFMA + argmax + routing + schedule (134 MB streamed)
  coarse_fused<<<B_ / 16, 512, 0, stream>>>(feat, cwPH, cwPL, cb, out0, out1,
                                            cnt, rowList, sched, nItems,
                                            doneCnt);
  // 3) expert MFMA + bias + softmax + argmax, full-K, no partials
  expert_fused<<<MAXI_X, 512, 0, stream>>>(feat, ewPH, ewPL, eb, rowList, cnt,
                                           sched, nItems, out2, out3);
}